// Round 2
// baseline (527.997 us; speedup 1.0000x reference)
//
#include <hip/hip_runtime.h>

// SeesawLoss on MI355X — R5.
// Inputs: d_in[0] = cls_score fp32 (8,16,512,512), d_in[1] = labels i32 (8,512,512),
//         d_in[2] = cum_samples fp32 (16). Output: d_out[0] = scalar loss fp32.
// ws layout (uint32 words):
//   [0 .. 255]     histogram, cacheline-spread: count for class c at word c*16
//   [256 .. 1279]  64 accumulator pairs, pair i at words 256 + i*16 (+0 nll, +1 mask)
//   [1280]         seesaw done-counter (fused final reduction)
//   [1281]         hist done-counter (plog tail)
//   [1344 .. 1359] plog[16] = P * log(clip(hist + cum, 1, inf))
// R3 (209 us): 1px/thread, 16 hoisted scalar loads, but serial prologue:
//   histp load -> barrier(vmcnt0) -> channel loads = two serial latency chains.
// R4 (306 us, FAILED): 4px/thread float4; compiler sank the 64-VGPR load clump
//   below the barrier to chase occupancy (VGPR=52, no spill) -> MLP destroyed.
// R5: back to R3's proven load codegen; plog precomputed in hist_k's done-counter
//   tail so seesaw_k has NO barrier and NO dependency before its channel loads;
//   plab folded into the existing c==lab select chain. Fused finalize kept.

constexpr int   kC       = 16;
constexpr int   kHW      = 512 * 512;              // 2^18
constexpr float kP       = 0.8f;                   // mitigation exponent
constexpr float kLogEps  = -4.605170185988091f;    // ln(0.01)
constexpr int   kNAcc    = 64;                     // spread accumulator pairs
constexpr int   kCtrSee  = 256 + kNAcc * 16;       // word 1280
constexpr int   kCtrHist = kCtrSee + 1;            // word 1281
constexpr int   kPlogW   = 1344;                   // 64 B-aligned plog region

__global__ __launch_bounds__(256) void init_ws_k(unsigned int* ws) {
    for (int i = threadIdx.x; i < kPlogW + 16; i += 256) ws[i] = 0u;
}

// 512 blocks (2/CU): block covers 16 KB of labels, 4 int4/thread hoisted.
// Tail: last block computes plog[16] once, so seesaw_k needs no histp prologue.
__global__ __launch_bounds__(256) void hist_k(const int4* __restrict__ lab4,
                                              const float* __restrict__ cum_in,
                                              unsigned int* __restrict__ ws) {
    int base = blockIdx.x * 1024 + threadIdx.x;
    int4 v[4];
    #pragma unroll
    for (int j = 0; j < 4; ++j) v[j] = lab4[base + j * 256];   // contiguous 4 KB per iter
    int cnt[16];
    #pragma unroll
    for (int c = 0; c < 16; ++c) cnt[c] = 0;
    #pragma unroll
    for (int j = 0; j < 4; ++j) {
        #pragma unroll
        for (int c = 0; c < 16; ++c)
            cnt[c] += (v[j].x == c) + (v[j].y == c) + (v[j].z == c) + (v[j].w == c);
    }
    #pragma unroll
    for (int c = 0; c < 16; ++c) {
        int x = cnt[c];
        #pragma unroll
        for (int off = 32; off > 0; off >>= 1) x += __shfl_down(x, off);
        cnt[c] = x;
    }
    __shared__ unsigned int sh[4 * 16];
    __shared__ int s_last;
    int wave = threadIdx.x >> 6, lane = threadIdx.x & 63;
    if (lane == 0) {
        #pragma unroll
        for (int c = 0; c < 16; ++c) sh[wave * 16 + c] = (unsigned)cnt[c];
    }
    __syncthreads();
    int t = threadIdx.x;
    if (t < 16)   // per-class slots 64 B apart
        atomicAdd(&ws[t * 16], sh[t] + sh[16 + t] + sh[32 + t] + sh[48 + t]);
    __syncthreads();                       // drain this block's atomics (vmcnt0)
    if (t == 0) {
        __threadfence();                   // release our histogram contribution
        unsigned d = atomicAdd(ws + kCtrHist, 1u);
        s_last = (d == gridDim.x - 1) ? 1 : 0;
    }
    __syncthreads();
    if (s_last && t < 16) {                // last block: histogram is complete
        __threadfence();                   // acquire side
        unsigned h = __hip_atomic_load(ws + t * 16,
                                       __ATOMIC_RELAXED, __HIP_MEMORY_SCOPE_AGENT);
        float cc = fmaxf((float)h + cum_in[t], 1.0f);      // clip(cum, 1, inf)
        ((float*)ws)[kPlogW + t] = kP * __logf(cc);
    }
}

// 1 pixel/thread, 8192 blocks x 256 threads. NO barrier, NO pre-load dependency:
// the 16 channel loads are the first thing issued. plog is a uniform 64 B read.
__global__ __launch_bounds__(256, 4) void seesaw_k(const float* __restrict__ cls,
                                                   const int*   __restrict__ labels,
                                                   const float* __restrict__ plogp,
                                                   unsigned int* __restrict__ ws,
                                                   float* __restrict__ out) {
    __shared__ float s_red[8];
    __shared__ int   s_last;
    int t  = threadIdx.x;
    int px = blockIdx.x * 256 + t;                 // grid exactly covers M
    int b  = px >> 18;
    int hw = px & (kHW - 1);
    const float* pbase = cls + (long long)b * kC * kHW + hw;

    float l[16];
    #pragma unroll
    for (int c = 0; c < 16; ++c) l[c] = pbase[(long long)c * kHW];  // 16 outstanding dwords
    int lab = labels[px];
    float pl[16];
    #pragma unroll
    for (int c = 0; c < 16; ++c) pl[c] = plogp[c];  // uniform addr: L2-hit broadcast/s_load

    float m1   = l[0];
    float llab = l[0];                              // select chains, no dynamic index
    float plab = pl[0];
    #pragma unroll
    for (int c = 1; c < 16; ++c) {
        m1 = fmaxf(m1, l[c]);
        if (c == lab) { llab = l[c]; plab = pl[c]; }
    }
    float s = 0.0f;
    #pragma unroll
    for (int c = 0; c < 16; ++c) s += __expf(l[c] - m1);
    // log(score_mat[c]) = l[c] - K, K = max(llab, m1 + log s + log EPS)
    float K = fmaxf(llab, m1 + __logf(s) + kLogEps);

    float m2 = -3.0e38f;
    #pragma unroll
    for (int c = 0; c < 16; ++c) {
        // adj = l + log(mit) + log(comp); both clamp to 0 at c==lab -> adj==llab
        float a = l[c] + fminf(0.0f, pl[c] - plab)
                       + fmaxf(0.0f, 2.0f * (l[c] - K));
        l[c] = a;
        m2 = fmaxf(m2, a);
    }
    float s2 = 0.0f;
    #pragma unroll
    for (int c = 0; c < 16; ++c) s2 += __expf(l[c] - m2);
    float nll = m2 + __logf(s2) - llab;             // -log_softmax(adj)[lab]

    float lsum = 0.0f, lcnt = 0.0f;
    if (lab != 0) { lsum = nll; lcnt = 1.0f; }      // ignore_index = 0
    #pragma unroll
    for (int off = 32; off > 0; off >>= 1) {
        lsum += __shfl_down(lsum, off);
        lcnt += __shfl_down(lcnt, off);
    }
    int wave = t >> 6, lane = t & 63;
    if (lane == 0) { s_red[wave] = lsum; s_red[4 + wave] = lcnt; }
    __syncthreads();
    if (t == 0) {
        float* pair = (float*)ws + 256 + (blockIdx.x & (kNAcc - 1)) * 16;  // 64 B-spread
        atomicAdd(&pair[0], s_red[0] + s_red[1] + s_red[2] + s_red[3]);
        atomicAdd(&pair[1], s_red[4] + s_red[5] + s_red[6] + s_red[7]);
        __threadfence();                                                   // release
        unsigned done = atomicAdd(ws + kCtrSee, 1u);
        s_last = (done == gridDim.x - 1) ? 1 : 0;
    }
    __syncthreads();
    if (s_last && t < 64) {                         // fused final reduction (last block)
        __threadfence();                            // acquire side
        float a  = __hip_atomic_load((float*)ws + 256 + t * 16,
                                     __ATOMIC_RELAXED, __HIP_MEMORY_SCOPE_AGENT);
        float bb = __hip_atomic_load((float*)ws + 256 + t * 16 + 1,
                                     __ATOMIC_RELAXED, __HIP_MEMORY_SCOPE_AGENT);
        #pragma unroll
        for (int off = 32; off > 0; off >>= 1) {
            a  += __shfl_down(a, off);
            bb += __shfl_down(bb, off);
        }
        if (t == 0) out[0] = a / bb;
    }
}

extern "C" void kernel_launch(void* const* d_in, const int* in_sizes, int n_in,
                              void* d_out, int out_size, void* d_ws, size_t ws_size,
                              hipStream_t stream) {
    const float* cls    = (const float*)d_in[0];
    const int*   labels = (const int*)d_in[1];
    const float* cum_in = (const float*)d_in[2];
    float* out = (float*)d_out;
    unsigned int* ws = (unsigned int*)d_ws;

    int M  = in_sizes[1];        // 2,097,152 pixels
    int n4 = M / 4;

    init_ws_k<<<1, 256, 0, stream>>>(ws);
    hist_k<<<n4 / 1024, 256, 0, stream>>>((const int4*)labels, cum_in, ws);
    seesaw_k<<<M / 256, 256, 0, stream>>>(cls, labels,
                                          (const float*)ws + kPlogW, ws, out);
}